// Round 4
// baseline (270.004 us; speedup 1.0000x reference)
//
#include <hip/hip_runtime.h>

constexpr int VOL = 32 * 32 * 32 * 32;   // 1048576 sites
constexpr float KAPPA = 0.1f;            // kappa/u0

// 8B vector: 2 consecutive x-sites per thread.
struct alignas(8) F2 { float x, y; };

__device__ __forceinline__ F2 operator+(F2 a, F2 b) { return F2{a.x + b.x, a.y + b.y}; }
__device__ __forceinline__ F2 operator-(F2 a, F2 b) { return F2{a.x - b.x, a.y - b.y}; }
__device__ __forceinline__ F2 operator*(F2 a, F2 b) { return F2{a.x * b.x, a.y * b.y}; }
__device__ __forceinline__ F2 operator*(float s, F2 a) { return F2{s * a.x, s * a.y}; }

__device__ __forceinline__ F2 ld2(const float* __restrict__ p, int idx) {
    return *reinterpret_cast<const F2*>(p + idx);
}

// --- spinor loaders: produce (re,im) F2 for spin s, color c ---
struct Direct {            // neighbor in y/z/t: same x-pair, different site
    const float* re; const float* im; int site;
    __device__ __forceinline__ void load(int s, int c, F2& r, F2& i) const {
        int idx = (s * 3 + c) * VOL + site;
        r = ld2(re, idx); i = ld2(im, idx);
    }
};
struct ShiftR {            // x+1 window {x+1,x+2}: {c.y, r.x}
    const float* re; const float* im; int cs, rs;
    __device__ __forceinline__ void load(int s, int c, F2& r, F2& i) const {
        int o = (s * 3 + c) * VOL;
        F2 cr = ld2(re, o + cs), rr = ld2(re, o + rs);
        F2 ci = ld2(im, o + cs), ri = ld2(im, o + rs);
        r = F2{cr.y, rr.x};
        i = F2{ci.y, ri.x};
    }
};
struct ShiftL {            // x-1 window {x-1,x}: {l.y, c.x}
    const float* re; const float* im; int ls, cs;
    __device__ __forceinline__ void load(int s, int c, F2& r, F2& i) const {
        int o = (s * 3 + c) * VOL;
        F2 lr = ld2(re, o + ls), cr = ld2(re, o + cs);
        F2 li = ld2(im, o + ls), ci = ld2(im, o + cs);
        r = F2{lr.y, cr.x};
        i = F2{li.y, ci.x};
    }
};

// --- U loaders ---
struct UDirect {
    const float* re; const float* im; int mu, site;
    __device__ __forceinline__ void load(int a, int b, F2& r, F2& i) const {
        int idx = ((a * 3 + b) * 4 + mu) * VOL + site;
        r = ld2(re, idx); i = ld2(im, idx);
    }
};
struct UShiftL {           // U_x at x-1 window {x-1,x}
    const float* re; const float* im; int mu, ls, cs;
    __device__ __forceinline__ void load(int a, int b, F2& r, F2& i) const {
        int o = ((a * 3 + b) * 4 + mu) * VOL;
        F2 lr = ld2(re, o + ls), cr = ld2(re, o + cs);
        F2 li = ld2(im, o + ls), ci = ld2(im, o + cs);
        r = F2{lr.y, cr.x};
        i = F2{li.y, ci.x};
    }
};

// One hopping term: project rows 0,1 of (I - S*gamma_mu)psi, multiply by U
// (S=+1) or U^dag (S=-1), reconstruct, accumulate REAL part only into dr.
// Im(chi) needed only for mu=0,2; Re(chi) only for mu=1,3 (compile-time pruned).
template <int MU, int S, class SL, class UL>
__device__ __forceinline__ void hop(const SL& sl, const UL& ul, F2 dr[4][3]) {
    constexpr bool DAG = (S < 0);
    constexpr bool NEEDI = (MU == 0 || MU == 2);
    const float s = (float)S;

    F2 hr[2][3], hi[2][3];
#pragma unroll
    for (int c = 0; c < 3; ++c) {
        F2 p0r, p0i, p1r, p1i, p2r, p2i, p3r, p3i;
        sl.load(0, c, p0r, p0i);
        sl.load(1, c, p1r, p1i);
        sl.load(2, c, p2r, p2i);
        sl.load(3, c, p3r, p3i);
        if (MU == 0) {
            hr[0][c] = p0r + s * p3i;  hi[0][c] = p0i - s * p3r;
            hr[1][c] = p1r + s * p2i;  hi[1][c] = p1i - s * p2r;
        } else if (MU == 1) {
            hr[0][c] = p0r + s * p3r;  hi[0][c] = p0i + s * p3i;
            hr[1][c] = p1r - s * p2r;  hi[1][c] = p1i - s * p2i;
        } else if (MU == 2) {
            hr[0][c] = p0r + s * p2i;  hi[0][c] = p0i - s * p2r;
            hr[1][c] = p1r - s * p3i;  hi[1][c] = p1i + s * p3r;
        } else {
            hr[0][c] = p0r - s * p2r;  hi[0][c] = p0i - s * p2i;
            hr[1][c] = p1r - s * p3r;  hi[1][c] = p1i - s * p3i;
        }
    }

    const float k = KAPPA, ks = KAPPA * s;
#pragma unroll
    for (int a = 0; a < 3; ++a) {
        // W[a][b] = DAG ? conj(U[b][a]) : U[a][b]
        F2 wr[3], wi[3];
#pragma unroll
        for (int b = 0; b < 3; ++b) {
            F2 r, i;
            if (DAG) { ul.load(b, a, r, i); wi[b] = F2{-i.x, -i.y}; }
            else     { ul.load(a, b, r, i); wi[b] = i; }
            wr[b] = r;
        }
        F2 ar0{0,0}, ar1{0,0}, ai0{0,0}, ai1{0,0};
#pragma unroll
        for (int b = 0; b < 3; ++b) {
            ar0 = ar0 + wr[b] * hr[0][b] - wi[b] * hi[0][b];
            ar1 = ar1 + wr[b] * hr[1][b] - wi[b] * hi[1][b];
            if (NEEDI) {
                ai0 = ai0 + wr[b] * hi[0][b] + wi[b] * hr[0][b];
                ai1 = ai1 + wr[b] * hi[1][b] + wi[b] * hr[1][b];
            }
        }
        dr[0][a] = dr[0][a] - k * ar0;
        dr[1][a] = dr[1][a] - k * ar1;
        if (MU == 0)      { dr[2][a] = dr[2][a] + ks * ai1; dr[3][a] = dr[3][a] + ks * ai0; }
        else if (MU == 1) { dr[2][a] = dr[2][a] + ks * ar1; dr[3][a] = dr[3][a] - ks * ar0; }
        else if (MU == 2) { dr[2][a] = dr[2][a] + ks * ai0; dr[3][a] = dr[3][a] - ks * ai1; }
        else              { dr[2][a] = dr[2][a] + ks * ar0; dr[3][a] = dr[3][a] + ks * ar1; }
    }
}

// grid = 2048 blocks; 8 XCDs; chunk = 256 logical blocks = t in [4i, 4i+4).
// Hardware round-robins original blockIdx across XCDs, so logical
// L = (b%8)*256 + b/8 gives each XCD a contiguous t-slab -> z/t neighbor
// reuse of src and U stays in that XCD's L2.
__global__ __launch_bounds__(256, 4)
void wilson_kernel(const float* __restrict__ src_re, const float* __restrict__ src_im,
                   const float* __restrict__ U_re, const float* __restrict__ U_im,
                   float* __restrict__ out) {
    int b = blockIdx.x;
    int L = (b & 7) * 256 + (b >> 3);
    int tid = L * 256 + threadIdx.x;
    int site = tid << 1;                 // 2 consecutive x-sites per thread

    int x2 = site & 31;
    int lbase = site & ~31;
    int sR = lbase | ((x2 + 2) & 31);    // right x-pair (wrapped)
    int sL = lbase | ((x2 + 30) & 31);   // left  x-pair (wrapped)

    int y = (site >> 5) & 31;
    int z = (site >> 10) & 31;
    int t = (site >> 15) & 31;
    int syp = (site & ~(31 << 5))  | (((y + 1)  & 31) << 5);
    int sym = (site & ~(31 << 5))  | (((y + 31) & 31) << 5);
    int szp = (site & ~(31 << 10)) | (((z + 1)  & 31) << 10);
    int szm = (site & ~(31 << 10)) | (((z + 31) & 31) << 10);
    int stp = (site & ~(31 << 15)) | (((t + 1)  & 31) << 15);
    int stm = (site & ~(31 << 15)) | (((t + 31) & 31) << 15);

    // central term: dest_re = src_re
    F2 dr[4][3];
#pragma unroll
    for (int s = 0; s < 4; ++s)
#pragma unroll
        for (int c = 0; c < 3; ++c)
            dr[s][c] = ld2(src_re, (s * 3 + c) * VOL + site);

    hop<0,  1>(ShiftR{src_re, src_im, site, sR}, UDirect{U_re, U_im, 0, site}, dr);
    hop<0, -1>(ShiftL{src_re, src_im, sL, site}, UShiftL{U_re, U_im, 0, sL, site}, dr);
    hop<1,  1>(Direct{src_re, src_im, syp},      UDirect{U_re, U_im, 1, site}, dr);
    hop<1, -1>(Direct{src_re, src_im, sym},      UDirect{U_re, U_im, 1, sym}, dr);
    hop<2,  1>(Direct{src_re, src_im, szp},      UDirect{U_re, U_im, 2, site}, dr);
    hop<2, -1>(Direct{src_re, src_im, szm},      UDirect{U_re, U_im, 2, szm}, dr);
    hop<3,  1>(Direct{src_re, src_im, stp},      UDirect{U_re, U_im, 3, site}, dr);
    hop<3, -1>(Direct{src_re, src_im, stm},      UDirect{U_re, U_im, 3, stm}, dr);

#pragma unroll
    for (int s = 0; s < 4; ++s)
#pragma unroll
        for (int c = 0; c < 3; ++c)
            *reinterpret_cast<F2*>(out + (s * 3 + c) * VOL + site) = dr[s][c];
}

extern "C" void kernel_launch(void* const* d_in, const int* in_sizes, int n_in,
                              void* d_out, int out_size, void* d_ws, size_t ws_size,
                              hipStream_t stream) {
    const float* src_re = (const float*)d_in[0];
    const float* src_im = (const float*)d_in[1];
    const float* U_re   = (const float*)d_in[2];
    const float* U_im   = (const float*)d_in[3];
    float* out = (float*)d_out;

    dim3 block(256);
    dim3 grid(VOL / 2 / 256);            // 2048 blocks, 2 sites per thread
    wilson_kernel<<<grid, block, 0, stream>>>(src_re, src_im, U_re, U_im, out);
}

// Round 5
// 238.892 us; speedup vs baseline: 1.1302x; 1.1302x over previous
//
#include <hip/hip_runtime.h>

constexpr int VOL = 32 * 32 * 32 * 32;   // 1048576 sites
constexpr float KAPPA = 0.1f;            // kappa/u0

// 16B-aligned 4-float vector (4 consecutive x-sites per thread).
struct alignas(16) F4 { float x, y, z, w; };
using f4v = __attribute__((ext_vector_type(4))) float;

__device__ __forceinline__ F4 operator+(F4 a, F4 b) { return F4{a.x + b.x, a.y + b.y, a.z + b.z, a.w + b.w}; }
__device__ __forceinline__ F4 operator-(F4 a, F4 b) { return F4{a.x - b.x, a.y - b.y, a.z - b.z, a.w - b.w}; }
__device__ __forceinline__ F4 operator*(F4 a, F4 b) { return F4{a.x * b.x, a.y * b.y, a.z * b.z, a.w * b.w}; }
__device__ __forceinline__ F4 operator*(float s, F4 a) { return F4{s * a.x, s * a.y, s * a.z, s * a.w}; }

__device__ __forceinline__ F4 ld4(const float* __restrict__ p, int idx) {
    return *reinterpret_cast<const F4*>(p + idx);
}
__device__ __forceinline__ void st_nt(float* __restrict__ p, F4 v) {
    f4v t = {v.x, v.y, v.z, v.w};
    __builtin_nontemporal_store(t, reinterpret_cast<f4v*>(p));
}

// --- spinor loaders: produce float4 (re,im) for spin s, color c ---
struct Direct {            // neighbor in y/z/t: same x-group, different site
    const float* re; const float* im; int site;
    __device__ __forceinline__ void load(int s, int c, F4& r, F4& i) const {
        int idx = (s * 3 + c) * VOL + site;
        r = ld4(re, idx); i = ld4(im, idx);
    }
};
struct ShiftR {            // x+1 window (x+1..x+4): {c.y,c.z,c.w,r.x}
    const float* re; const float* im; int cs, rs;
    __device__ __forceinline__ void load(int s, int c, F4& r, F4& i) const {
        int o = (s * 3 + c) * VOL;
        F4 cr = ld4(re, o + cs), rr = ld4(re, o + rs);
        F4 ci = ld4(im, o + cs), ri = ld4(im, o + rs);
        r = F4{cr.y, cr.z, cr.w, rr.x};
        i = F4{ci.y, ci.z, ci.w, ri.x};
    }
};
struct ShiftL {            // x-1 window (x-1..x+2): {l.w,c.x,c.y,c.z}
    const float* re; const float* im; int ls, cs;
    __device__ __forceinline__ void load(int s, int c, F4& r, F4& i) const {
        int o = (s * 3 + c) * VOL;
        F4 lr = ld4(re, o + ls), cr = ld4(re, o + cs);
        F4 li = ld4(im, o + ls), ci = ld4(im, o + cs);
        r = F4{lr.w, cr.x, cr.y, cr.z};
        i = F4{li.w, ci.x, ci.y, ci.z};
    }
};

// --- U loaders: produce float4 (re,im) of U[a][b] at the link site ---
struct UDirect {
    const float* re; const float* im; int mu, site;
    __device__ __forceinline__ void load(int a, int b, F4& r, F4& i) const {
        int idx = ((a * 3 + b) * 4 + mu) * VOL + site;
        r = ld4(re, idx); i = ld4(im, idx);
    }
};
struct UShiftL {           // U_x at x-1..x+2 window
    const float* re; const float* im; int mu, ls, cs;
    __device__ __forceinline__ void load(int a, int b, F4& r, F4& i) const {
        int o = ((a * 3 + b) * 4 + mu) * VOL;
        F4 lr = ld4(re, o + ls), cr = ld4(re, o + cs);
        F4 li = ld4(im, o + ls), ci = ld4(im, o + cs);
        r = F4{lr.w, cr.x, cr.y, cr.z};
        i = F4{li.w, ci.x, ci.y, ci.z};
    }
};

// One hopping term: project rows 0,1 of (I - S*gamma_mu)psi, multiply by U
// (S=+1) or U^dag (S=-1), reconstruct, accumulate REAL part only into dr.
// Im(chi) needed only for mu=0,2; Re(chi) only for mu=1,3 (compile-time pruned).
template <int MU, int S, class SL, class UL>
__device__ __forceinline__ void hop(const SL& sl, const UL& ul, F4 dr[4][3]) {
    constexpr bool DAG = (S < 0);
    constexpr bool NEEDI = (MU == 0 || MU == 2);
    const float s = (float)S;

    F4 hr[2][3], hi[2][3];
#pragma unroll
    for (int c = 0; c < 3; ++c) {
        F4 p0r, p0i, p1r, p1i, p2r, p2i, p3r, p3i;
        sl.load(0, c, p0r, p0i);
        sl.load(1, c, p1r, p1i);
        sl.load(2, c, p2r, p2i);
        sl.load(3, c, p3r, p3i);
        if (MU == 0) {
            hr[0][c] = p0r + s * p3i;  hi[0][c] = p0i - s * p3r;
            hr[1][c] = p1r + s * p2i;  hi[1][c] = p1i - s * p2r;
        } else if (MU == 1) {
            hr[0][c] = p0r + s * p3r;  hi[0][c] = p0i + s * p3i;
            hr[1][c] = p1r - s * p2r;  hi[1][c] = p1i - s * p2i;
        } else if (MU == 2) {
            hr[0][c] = p0r + s * p2i;  hi[0][c] = p0i - s * p2r;
            hr[1][c] = p1r - s * p3i;  hi[1][c] = p1i + s * p3r;
        } else {
            hr[0][c] = p0r - s * p2r;  hi[0][c] = p0i - s * p2i;
            hr[1][c] = p1r - s * p3r;  hi[1][c] = p1i - s * p3i;
        }
    }

    const float k = KAPPA, ks = KAPPA * s;
#pragma unroll
    for (int a = 0; a < 3; ++a) {
        // W[a][b] = DAG ? conj(U[b][a]) : U[a][b]
        F4 wr[3], wi[3];
#pragma unroll
        for (int b = 0; b < 3; ++b) {
            F4 r, i;
            if (DAG) { ul.load(b, a, r, i); wi[b] = F4{-i.x, -i.y, -i.z, -i.w}; }
            else     { ul.load(a, b, r, i); wi[b] = i; }
            wr[b] = r;
        }
        F4 ar0{0,0,0,0}, ar1{0,0,0,0}, ai0{0,0,0,0}, ai1{0,0,0,0};
#pragma unroll
        for (int b = 0; b < 3; ++b) {
            ar0 = ar0 + wr[b] * hr[0][b] - wi[b] * hi[0][b];
            ar1 = ar1 + wr[b] * hr[1][b] - wi[b] * hi[1][b];
            if (NEEDI) {
                ai0 = ai0 + wr[b] * hi[0][b] + wi[b] * hr[0][b];
                ai1 = ai1 + wr[b] * hi[1][b] + wi[b] * hr[1][b];
            }
        }
        dr[0][a] = dr[0][a] - k * ar0;
        dr[1][a] = dr[1][a] - k * ar1;
        if (MU == 0)      { dr[2][a] = dr[2][a] + ks * ai1; dr[3][a] = dr[3][a] + ks * ai0; }
        else if (MU == 1) { dr[2][a] = dr[2][a] + ks * ar1; dr[3][a] = dr[3][a] - ks * ar0; }
        else if (MU == 2) { dr[2][a] = dr[2][a] + ks * ai0; dr[3][a] = dr[3][a] - ks * ai1; }
        else              { dr[2][a] = dr[2][a] + ks * ar0; dr[3][a] = dr[3][a] + ks * ar1; }
    }
}

// 1024 blocks, each = one full (x,y) plane (fixed z,t); 4 sites/thread.
// HW round-robins physical block b to XCD b%8. Swizzle to logical
// L = (b&7)*128 + (b>>3): XCD k owns t in [4k,4k+4), all z. Then z+-1
// neighbors (L+-1) and 3/4 of t+-1 neighbors (L+-32) are XCD-local ->
// the src z-halo (201 MB) and U_z refetch (75 MB) become L2 hits instead
// of fabric traffic (R3 FETCH model: 302+75+100+201 = 679 ~= measured 684).
__global__ __launch_bounds__(256)
void wilson_kernel(const float* __restrict__ src_re, const float* __restrict__ src_im,
                   const float* __restrict__ U_re, const float* __restrict__ U_im,
                   float* __restrict__ out) {
    int b = blockIdx.x;
    int L = (b & 7) * 128 + (b >> 3);
    int tid = L * 256 + threadIdx.x;
    int site = tid << 2;                 // 4 consecutive x-sites per thread

    int x4 = site & 31;                  // x of group start (multiple of 4)
    int lbase = site & ~31;
    int sR = lbase | ((x4 + 4) & 31);    // right x-group (wrapped)
    int sL = lbase | ((x4 + 28) & 31);   // left  x-group (wrapped)

    int y = (site >> 5) & 31;
    int z = (site >> 10) & 31;
    int t = (site >> 15) & 31;
    int syp = (site & ~(31 << 5))  | (((y + 1)  & 31) << 5);
    int sym = (site & ~(31 << 5))  | (((y + 31) & 31) << 5);
    int szp = (site & ~(31 << 10)) | (((z + 1)  & 31) << 10);
    int szm = (site & ~(31 << 10)) | (((z + 31) & 31) << 10);
    int stp = (site & ~(31 << 15)) | (((t + 1)  & 31) << 15);
    int stm = (site & ~(31 << 15)) | (((t + 31) & 31) << 15);

    // central term: dest_re = src_re
    F4 dr[4][3];
#pragma unroll
    for (int s = 0; s < 4; ++s)
#pragma unroll
        for (int c = 0; c < 3; ++c)
            dr[s][c] = ld4(src_re, (s * 3 + c) * VOL + site);

    hop<0,  1>(ShiftR{src_re, src_im, site, sR},   UDirect{U_re, U_im, 0, site}, dr);
    hop<0, -1>(ShiftL{src_re, src_im, sL, site},   UShiftL{U_re, U_im, 0, sL, site}, dr);
    hop<1,  1>(Direct{src_re, src_im, syp},        UDirect{U_re, U_im, 1, site}, dr);
    hop<1, -1>(Direct{src_re, src_im, sym},        UDirect{U_re, U_im, 1, sym}, dr);
    hop<2,  1>(Direct{src_re, src_im, szp},        UDirect{U_re, U_im, 2, site}, dr);
    hop<2, -1>(Direct{src_re, src_im, szm},        UDirect{U_re, U_im, 2, szm}, dr);
    hop<3,  1>(Direct{src_re, src_im, stp},        UDirect{U_re, U_im, 3, site}, dr);
    hop<3, -1>(Direct{src_re, src_im, stm},        UDirect{U_re, U_im, 3, stm}, dr);

    // non-temporal: out is write-once, keep it from evicting U/src in L2
#pragma unroll
    for (int s = 0; s < 4; ++s)
#pragma unroll
        for (int c = 0; c < 3; ++c)
            st_nt(out + (s * 3 + c) * VOL + site, dr[s][c]);
}

extern "C" void kernel_launch(void* const* d_in, const int* in_sizes, int n_in,
                              void* d_out, int out_size, void* d_ws, size_t ws_size,
                              hipStream_t stream) {
    const float* src_re = (const float*)d_in[0];
    const float* src_im = (const float*)d_in[1];
    const float* U_re   = (const float*)d_in[2];
    const float* U_im   = (const float*)d_in[3];
    float* out = (float*)d_out;

    dim3 block(256);
    dim3 grid(VOL / 4 / 256);            // 1024 blocks, 4 sites per thread
    wilson_kernel<<<grid, block, 0, stream>>>(src_re, src_im, U_re, U_im, out);
}

// Round 6
// 152.542 us; speedup vs baseline: 1.7700x; 1.5661x over previous
//
#include <hip/hip_runtime.h>

constexpr int VOL = 32 * 32 * 32 * 32;   // 1048576 sites
constexpr float KAPPA = 0.1f;            // kappa/u0

// 8B vector: 2 consecutive x-sites per thread (math verified in R4).
struct alignas(8) F2 { float x, y; };
using f2v = __attribute__((ext_vector_type(2))) float;

__device__ __forceinline__ F2 operator+(F2 a, F2 b) { return F2{a.x + b.x, a.y + b.y}; }
__device__ __forceinline__ F2 operator-(F2 a, F2 b) { return F2{a.x - b.x, a.y - b.y}; }
__device__ __forceinline__ F2 operator*(F2 a, F2 b) { return F2{a.x * b.x, a.y * b.y}; }
__device__ __forceinline__ F2 operator*(float s, F2 a) { return F2{s * a.x, s * a.y}; }

__device__ __forceinline__ F2 ld2(const float* __restrict__ p, int idx) {
    return *reinterpret_cast<const F2*>(p + idx);
}
__device__ __forceinline__ void st_nt2(float* __restrict__ p, F2 v) {
    f2v t = {v.x, v.y};
    __builtin_nontemporal_store(t, reinterpret_cast<f2v*>(p));
}

// ---- global spinor loader (z/t hops, y-boundary rows) ----
struct Direct {
    const float* re; const float* im; int site;
    __device__ __forceinline__ void load(int s, int c, F2& r, F2& i) const {
        int idx = (s * 3 + c) * VOL + site;
        r = ld2(re, idx); i = ld2(im, idx);
    }
};

// ---- LDS spinor loaders. lds[24][512]: plane (s*3+c)*2+ri, site q=ly*32+lx ----
struct LDSDirect {
    const float (*L)[512]; int q;
    __device__ __forceinline__ void load(int s, int c, F2& r, F2& i) const {
        int k = (s * 3 + c) * 2;
        r = *reinterpret_cast<const F2*>(&L[k][q]);
        i = *reinterpret_cast<const F2*>(&L[k + 1][q]);
    }
};
struct LDSShift {                       // two arbitrary float indices (x+-1 windows)
    const float (*L)[512]; int i0, i1;
    __device__ __forceinline__ void load(int s, int c, F2& r, F2& i) const {
        int k = (s * 3 + c) * 2;
        r = F2{L[k][i0], L[k][i1]};
        i = F2{L[k + 1][i0], L[k + 1][i1]};
    }
};

// ---- U loaders ----
struct UDirect {
    const float* re; const float* im; int mu, site;
    __device__ __forceinline__ void load(int a, int b, F2& r, F2& i) const {
        int idx = ((a * 3 + b) * 4 + mu) * VOL + site;
        r = ld2(re, idx); i = ld2(im, idx);
    }
};
struct URegs {                          // preloaded central U_x
    const F2* r; const F2* i;
    __device__ __forceinline__ void load(int a, int b, F2& rr, F2& ii) const {
        rr = r[a * 3 + b]; ii = i[a * 3 + b];
    }
};
struct UShiftRegs {                     // U_x at {x-1, x}: boundary scalar + central.x
    const F2* cr; const F2* ci; const float* blr; const float* bli;
    __device__ __forceinline__ void load(int a, int b, F2& rr, F2& ii) const {
        int e = a * 3 + b;
        rr = F2{blr[e], cr[e].x};
        ii = F2{bli[e], ci[e].x};
    }
};

// One hopping term: project rows 0,1 of (I - S*gamma_mu)psi, multiply by U
// (S=+1) or U^dag (S=-1), reconstruct, accumulate REAL part only into dr.
// Im(chi) needed only for mu=0,2; Re(chi) only for mu=1,3 (compile-time pruned).
template <int MU, int S, class SL, class UL>
__device__ __forceinline__ void hop(const SL& sl, const UL& ul, F2 dr[4][3]) {
    constexpr bool DAG = (S < 0);
    constexpr bool NEEDI = (MU == 0 || MU == 2);
    const float s = (float)S;

    F2 hr[2][3], hi[2][3];
#pragma unroll
    for (int c = 0; c < 3; ++c) {
        F2 p0r, p0i, p1r, p1i, p2r, p2i, p3r, p3i;
        sl.load(0, c, p0r, p0i);
        sl.load(1, c, p1r, p1i);
        sl.load(2, c, p2r, p2i);
        sl.load(3, c, p3r, p3i);
        if (MU == 0) {
            hr[0][c] = p0r + s * p3i;  hi[0][c] = p0i - s * p3r;
            hr[1][c] = p1r + s * p2i;  hi[1][c] = p1i - s * p2r;
        } else if (MU == 1) {
            hr[0][c] = p0r + s * p3r;  hi[0][c] = p0i + s * p3i;
            hr[1][c] = p1r - s * p2r;  hi[1][c] = p1i - s * p2i;
        } else if (MU == 2) {
            hr[0][c] = p0r + s * p2i;  hi[0][c] = p0i - s * p2r;
            hr[1][c] = p1r - s * p3i;  hi[1][c] = p1i + s * p3r;
        } else {
            hr[0][c] = p0r - s * p2r;  hi[0][c] = p0i - s * p2i;
            hr[1][c] = p1r - s * p3r;  hi[1][c] = p1i - s * p3i;
        }
    }

    const float k = KAPPA, ks = KAPPA * s;
#pragma unroll
    for (int a = 0; a < 3; ++a) {
        F2 wr[3], wi[3];
#pragma unroll
        for (int b = 0; b < 3; ++b) {
            F2 r, i;
            if (DAG) { ul.load(b, a, r, i); wi[b] = F2{-i.x, -i.y}; }
            else     { ul.load(a, b, r, i); wi[b] = i; }
            wr[b] = r;
        }
        F2 ar0{0,0}, ar1{0,0}, ai0{0,0}, ai1{0,0};
#pragma unroll
        for (int b = 0; b < 3; ++b) {
            ar0 = ar0 + wr[b] * hr[0][b] - wi[b] * hi[0][b];
            ar1 = ar1 + wr[b] * hr[1][b] - wi[b] * hi[1][b];
            if (NEEDI) {
                ai0 = ai0 + wr[b] * hi[0][b] + wi[b] * hr[0][b];
                ai1 = ai1 + wr[b] * hi[1][b] + wi[b] * hr[1][b];
            }
        }
        dr[0][a] = dr[0][a] - k * ar0;
        dr[1][a] = dr[1][a] - k * ar1;
        if (MU == 0)      { dr[2][a] = dr[2][a] + ks * ai1; dr[3][a] = dr[3][a] + ks * ai0; }
        else if (MU == 1) { dr[2][a] = dr[2][a] + ks * ar1; dr[3][a] = dr[3][a] - ks * ar0; }
        else if (MU == 2) { dr[2][a] = dr[2][a] + ks * ai0; dr[3][a] = dr[3][a] - ks * ai1; }
        else              { dr[2][a] = dr[2][a] + ks * ar0; dr[3][a] = dr[3][a] + ks * ar1; }
    }
}

// Block = half xy-plane (y in [16h,16h+16), fixed z,t), 256 threads x F2 = 512
// sites. The block's spinor (re+im, 48 KB) is staged in LDS; central, x+-, and
// interior y+- hops read LDS (not the VMEM queue, which R2-R5 show is the
// binding resource at ~25 GB/s/CU). z/t hops + U stream from global with the
// XCD t-slab swizzle (R5: FETCH 684->542 MB confirmed).
__global__ __launch_bounds__(256)
void wilson_kernel(const float* __restrict__ src_re, const float* __restrict__ src_im,
                   const float* __restrict__ U_re, const float* __restrict__ U_im,
                   float* __restrict__ out) {
    __shared__ float lds[24][512];

    int b = blockIdx.x;                  // 2048 blocks
    int L = (b & 7) * 256 + (b >> 3);    // XCD k owns t in [4k,4k+4)
    int h = L & 1;                       // y-half
    int p = L >> 1;                      // plane: z = p&31, t = p>>5
    int z = p & 31, t = p >> 5;

    int q  = threadIdx.x * 2;            // site index within half-plane (0..510)
    int lx = q & 31, ly = q >> 5;        // x, local row
    int y  = (h << 4) | ly;
    int site = (((((t << 5) | z) << 5) | y) << 5) | lx;

    // ---- stage own spinor into LDS; init central term from the same values ----
    F2 dr[4][3];
#pragma unroll
    for (int k = 0; k < 12; ++k) {
        F2 r = ld2(src_re, k * VOL + site);
        F2 i = ld2(src_im, k * VOL + site);
        *reinterpret_cast<F2*>(&lds[2 * k][q])     = r;
        *reinterpret_cast<F2*>(&lds[2 * k + 1][q]) = i;
        dr[k / 3][k % 3] = r;
    }
    __syncthreads();

    // ---- x hops: spinor from LDS, U_x loaded once into registers ----
    int row = ly * 32;
    int iR0 = row + ((lx + 1) & 31), iR1 = row + ((lx + 2) & 31);
    int iL0 = row + ((lx + 31) & 31);
    int gxm1 = (site & ~31) | ((lx + 31) & 31);   // global site of x-1

    F2 uxr[9], uxi[9];
    float blr[9], bli[9];
#pragma unroll
    for (int e = 0; e < 9; ++e) {
        uxr[e] = ld2(U_re, (e * 4 + 0) * VOL + site);
        uxi[e] = ld2(U_im, (e * 4 + 0) * VOL + site);
        blr[e] = U_re[(e * 4 + 0) * VOL + gxm1];
        bli[e] = U_im[(e * 4 + 0) * VOL + gxm1];
    }
    hop<0,  1>(LDSShift{lds, iR0, iR1}, URegs{uxr, uxi}, dr);
    hop<0, -1>(LDSShift{lds, iL0, q},   UShiftRegs{uxr, uxi, blr, bli}, dr);

    // ---- y hops: interior rows from LDS, boundary rows from global ----
    int syp = (site & ~(31 << 5)) | (((y + 1)  & 31) << 5);
    int sym = (site & ~(31 << 5)) | (((y + 31) & 31) << 5);
    if (ly < 15)
        hop<1,  1>(LDSDirect{lds, q + 32}, UDirect{U_re, U_im, 1, site}, dr);
    else
        hop<1,  1>(Direct{src_re, src_im, syp}, UDirect{U_re, U_im, 1, site}, dr);
    if (ly > 0)
        hop<1, -1>(LDSDirect{lds, q - 32}, UDirect{U_re, U_im, 1, sym}, dr);
    else
        hop<1, -1>(Direct{src_re, src_im, sym}, UDirect{U_re, U_im, 1, sym}, dr);

    // ---- z, t hops: global (L2-local via XCD swizzle) ----
    int szp = (site & ~(31 << 10)) | (((z + 1)  & 31) << 10);
    int szm = (site & ~(31 << 10)) | (((z + 31) & 31) << 10);
    int stp = (site & ~(31 << 15)) | (((t + 1)  & 31) << 15);
    int stm = (site & ~(31 << 15)) | (((t + 31) & 31) << 15);

    hop<2,  1>(Direct{src_re, src_im, szp}, UDirect{U_re, U_im, 2, site}, dr);
    hop<2, -1>(Direct{src_re, src_im, szm}, UDirect{U_re, U_im, 2, szm}, dr);
    hop<3,  1>(Direct{src_re, src_im, stp}, UDirect{U_re, U_im, 3, site}, dr);
    hop<3, -1>(Direct{src_re, src_im, stm}, UDirect{U_re, U_im, 3, stm}, dr);

    // ---- store real part, non-temporal ----
#pragma unroll
    for (int s = 0; s < 4; ++s)
#pragma unroll
        for (int c = 0; c < 3; ++c)
            st_nt2(out + (s * 3 + c) * VOL + site, dr[s][c]);
}

extern "C" void kernel_launch(void* const* d_in, const int* in_sizes, int n_in,
                              void* d_out, int out_size, void* d_ws, size_t ws_size,
                              hipStream_t stream) {
    const float* src_re = (const float*)d_in[0];
    const float* src_im = (const float*)d_in[1];
    const float* U_re   = (const float*)d_in[2];
    const float* U_im   = (const float*)d_in[3];
    float* out = (float*)d_out;

    dim3 block(256);
    dim3 grid(VOL / 2 / 256);            // 2048 blocks, 2 sites per thread
    wilson_kernel<<<grid, block, 0, stream>>>(src_re, src_im, U_re, U_im, out);
}